// Round 1
// baseline (650.678 us; speedup 1.0000x reference)
//
#include <hip/hip_runtime.h>

#define HH 64

static __global__ void k_set_ones(unsigned char* __restrict__ p, int n){
  int i = blockIdx.x * blockDim.x + threadIdx.x;
  if (i < n) p[i] = 1;
}

// Dense MLP evaluation: out[a,b,c] = sigmoid(MLP(p(c), p(b), p(a)))
// p(t) = (t*s + 0.5)/129 * 2 - 1  (x varies fastest = last index)
static __global__ __launch_bounds__(256) void k_eval_mlp(
    const float* __restrict__ w1, const float* __restrict__ b1,
    const float* __restrict__ w2, const float* __restrict__ b2,
    const float* __restrict__ w3, const float* __restrict__ b3,
    float* __restrict__ out, int R, int s)
{
  __shared__ float sw1[3*HH];
  __shared__ float sb1[HH];
  __shared__ float sw2t[HH*HH];   // transposed: sw2t[j*64+i] = w2[i*64+j]
  __shared__ float sb2[HH];
  __shared__ float sw3[HH];
  __shared__ float sb3s[1];
  const int t = threadIdx.x;
  for (int idx = t; idx < HH*HH; idx += 256){
    int i = idx >> 6, j = idx & 63;
    sw2t[j*HH + i] = w2[idx];
  }
  if (t < 3*HH) sw1[t] = w1[t];
  if (t < HH){ sb1[t] = b1[t]; sb2[t] = b2[t]; sw3[t] = w3[t]; }
  if (t == 0) sb3s[0] = b3[0];
  __syncthreads();
  const unsigned int n = (unsigned int)R * (unsigned int)R * (unsigned int)R;
  unsigned int gid = blockIdx.x * 256u + (unsigned int)t;
  if (gid >= n) return;
  const unsigned int c = gid % (unsigned int)R;
  const unsigned int r = gid / (unsigned int)R;
  const unsigned int b = r % (unsigned int)R;
  const unsigned int a = r / (unsigned int)R;
  const float x = ((float)(c * (unsigned int)s) + 0.5f) / 129.0f * 2.0f - 1.0f;
  const float y = ((float)(b * (unsigned int)s) + 0.5f) / 129.0f * 2.0f - 1.0f;
  const float z = ((float)(a * (unsigned int)s) + 0.5f) / 129.0f * 2.0f - 1.0f;
  float h1[HH];
  #pragma unroll
  for (int i = 0; i < HH; ++i){
    float v = sb1[i];
    v = fmaf(x, sw1[i],       v);
    v = fmaf(y, sw1[HH + i],  v);
    v = fmaf(z, sw1[2*HH + i], v);
    h1[i] = fmaxf(v, 0.0f);
  }
  float o = sb3s[0];
  #pragma unroll 4
  for (int j = 0; j < HH; ++j){
    float acc = sb2[j];
    const float* wr = &sw2t[j*HH];
    #pragma unroll
    for (int i = 0; i < HH; ++i) acc = fmaf(h1[i], wr[i], acc);
    o = fmaf(fmaxf(acc, 0.0f), sw3[j], o);
  }
  out[gid] = 1.0f / (1.0f + expf(-o));
}

// Per-level: trilinear upsample prev (Rp^3 -> R^3, coords exactly i/2),
// boundary-seed mask (interpolated binarization strictly in (0,1)),
// sign-mismatch mask, and the upsampled "calculated" mask.
static __global__ __launch_bounds__(256) void k_resize_boundary(
    const float* __restrict__ prev,            // Rp^3
    const float* __restrict__ occ_true,        // R^3
    const unsigned char* __restrict__ calc_prev, // Rp^3
    float* __restrict__ occ_i,                 // R^3
    unsigned char* __restrict__ bnd0,          // R^3
    unsigned char* __restrict__ mism,          // R^3
    unsigned char* __restrict__ calc_out,      // R^3
    int R, int Rp)
{
  const unsigned int n = (unsigned int)R * (unsigned int)R * (unsigned int)R;
  unsigned int gid = blockIdx.x * 256u + threadIdx.x;
  if (gid >= n) return;
  int c = (int)(gid % (unsigned int)R);
  unsigned int r = gid / (unsigned int)R;
  int b = (int)(r % (unsigned int)R);
  int a = (int)(r / (unsigned int)R);
  int a0 = a >> 1, da = a & 1;
  int b0i = b >> 1, db = b & 1;
  int c0 = c >> 1, dc = c & 1;
  float sum = 0.0f;
  int cnt = 0;
  const int tot = (da + 1) * (db + 1) * (dc + 1);
  for (int dz = 0; dz <= da; ++dz)
    for (int dy = 0; dy <= db; ++dy)
      for (int dx = 0; dx <= dc; ++dx){
        float v = prev[((unsigned int)(a0 + dz) * (unsigned int)Rp + (unsigned int)(b0i + dy)) * (unsigned int)Rp + (unsigned int)(c0 + dx)];
        sum += v;
        cnt += (v > 0.5f) ? 1 : 0;
      }
  float oi = sum / (float)tot;          // tot in {1,2,4,8}: exact
  occ_i[gid] = oi;
  bnd0[gid] = (cnt > 0 && cnt < tot) ? 1 : 0;
  mism[gid] = ((oi - 0.5f) * (occ_true[gid] - 0.5f) < 0.0f) ? 1 : 0;
  calc_out[gid] = ((da | db | dc) == 0)
      ? calc_prev[((unsigned int)a0 * (unsigned int)Rp + (unsigned int)b0i) * (unsigned int)Rp + (unsigned int)c0]
      : (unsigned char)0;
}

// nb = dilate3(src) & ~calc ; calc |= nb ; conf_out = nb & mism ; upd |= nb
static __global__ __launch_bounds__(256) void k_dilate_step(
    const unsigned char* __restrict__ src,
    const unsigned char* __restrict__ mism,
    unsigned char* __restrict__ calc,
    unsigned char* __restrict__ conf_out,
    unsigned char* __restrict__ upd,
    int R, int first)
{
  const unsigned int n = (unsigned int)R * (unsigned int)R * (unsigned int)R;
  unsigned int gid = blockIdx.x * 256u + threadIdx.x;
  if (gid >= n) return;
  int c = (int)(gid % (unsigned int)R);
  unsigned int r = gid / (unsigned int)R;
  int b = (int)(r % (unsigned int)R);
  int a = (int)(r / (unsigned int)R);
  int m = 0;
  for (int dz = -1; dz <= 1; ++dz){
    int az = a + dz; if (az < 0 || az >= R) continue;
    for (int dy = -1; dy <= 1; ++dy){
      int by = b + dy; if (by < 0 || by >= R) continue;
      for (int dx = -1; dx <= 1; ++dx){
        int cx = c + dx; if (cx < 0 || cx >= R) continue;
        m |= src[((unsigned int)az * (unsigned int)R + (unsigned int)by) * (unsigned int)R + (unsigned int)cx];
      }
    }
  }
  unsigned char nb = (m && !calc[gid]) ? (unsigned char)1 : (unsigned char)0;
  if (nb) calc[gid] = 1;
  conf_out[gid] = (nb && mism[gid]) ? (unsigned char)1 : (unsigned char)0;
  if (first) upd[gid] = nb;
  else if (nb) upd[gid] = 1;
}

static __global__ __launch_bounds__(256) void k_combine(
    const float* __restrict__ occ_true, const float* __restrict__ occ_i,
    const unsigned char* __restrict__ upd, float* __restrict__ out, unsigned int n)
{
  unsigned int gid = blockIdx.x * 256u + threadIdx.x;
  if (gid < n) out[gid] = upd[gid] ? occ_true[gid] : occ_i[gid];
}

extern "C" void kernel_launch(void* const* d_in, const int* in_sizes, int n_in,
                              void* d_out, int out_size, void* d_ws, size_t ws_size,
                              hipStream_t stream)
{
  const float* w1 = (const float*)d_in[0];
  const float* b1 = (const float*)d_in[1];
  const float* w2 = (const float*)d_in[2];
  const float* b2 = (const float*)d_in[3];
  const float* w3 = (const float*)d_in[4];
  const float* b3 = (const float*)d_in[5];
  float* out = (float*)d_out;

  const int NF = 129 * 129 * 129;  // 2146689
  const int NP = 65 * 65 * 65;     // 274625
  char* ws = (char*)d_ws;
  size_t off = 0;
  auto alloc = [&](size_t bytes) -> void* {
    void* p = (void*)(ws + off);
    off += (bytes + 255) & ~(size_t)255;
    return p;
  };
  float* f_true  = (float*)alloc((size_t)NF * 4);
  float* f_occi  = (float*)alloc((size_t)NF * 4);
  float* f_prevA = (float*)alloc((size_t)NP * 4);
  float* f_prevB = (float*)alloc((size_t)NP * 4);
  unsigned char* b_b0    = (unsigned char*)alloc(NF);
  unsigned char* b_mism  = (unsigned char*)alloc(NF);
  unsigned char* b_confA = (unsigned char*)alloc(NF);
  unsigned char* b_confB = (unsigned char*)alloc(NF);
  unsigned char* b_calcA = (unsigned char*)alloc(NF);
  unsigned char* b_calcB = (unsigned char*)alloc(NF);
  unsigned char* b_upd   = (unsigned char*)alloc(NF);
  (void)ws_size;

  // Level 0: R=17 dense eval; calculated mask at 17^3 is all-true.
  {
    int R = 17, s = 8;
    int n = R * R * R;
    k_eval_mlp<<<(n + 255) / 256, 256, 0, stream>>>(w1, b1, w2, b2, w3, b3, f_prevA, R, s);
    k_set_ones<<<(n + 255) / 256, 256, 0, stream>>>(b_calcA, n);
  }

  int Rp = 17;
  float* prev = f_prevA;
  unsigned char* calcP = b_calcA;
  unsigned char* calcC = b_calcB;
  for (int li = 1; li <= 3; ++li){
    int R = 2 * Rp - 1;
    int s = 128 / (R - 1);
    unsigned int n = (unsigned int)R * (unsigned int)R * (unsigned int)R;
    int blocks = (int)((n + 255u) / 256u);
    float* occ_out = (li == 3) ? out : ((prev == f_prevA) ? f_prevB : f_prevA);

    k_eval_mlp<<<blocks, 256, 0, stream>>>(w1, b1, w2, b2, w3, b3, f_true, R, s);
    k_resize_boundary<<<blocks, 256, 0, stream>>>(prev, f_true, calcP, f_occi, b_b0, b_mism, calcC, R, Rp);
    // boundary pass, then two conflict-propagation passes (N_CONFLICT_ITERS=2)
    k_dilate_step<<<blocks, 256, 0, stream>>>(b_b0,    b_mism, calcC, b_confA, b_upd, R, 1);
    k_dilate_step<<<blocks, 256, 0, stream>>>(b_confA, b_mism, calcC, b_confB, b_upd, R, 0);
    k_dilate_step<<<blocks, 256, 0, stream>>>(b_confB, b_mism, calcC, b_confA, b_upd, R, 0);
    k_combine<<<blocks, 256, 0, stream>>>(f_true, f_occi, b_upd, occ_out, n);

    prev = occ_out;
    unsigned char* tmpc = calcP; calcP = calcC; calcC = tmpc;
    Rp = R;
  }
  (void)in_sizes; (void)n_in; (void)out_size;
}